// Round 8
// baseline (133.178 us; speedup 1.0000x reference)
//
#include <hip/hip_runtime.h>

#define N_NODES 10000
#define N_EDGES 320000
#define D 256
#define BUCKET 128   // int2 slots per node; degree ~ Binom(320K,1e-4), mean 32, sigma 5.7

typedef __attribute__((ext_vector_type(8))) short bf16x8;
typedef __attribute__((ext_vector_type(4))) float f32x4;

__device__ __forceinline__ float relu(float x) { return x > 0.0f ? x : 0.0f; }

__device__ __forceinline__ ushort f2bf(float f) {
    union { float f; unsigned u; } c; c.f = f;
    unsigned u = c.u;
    u += 0x7FFF + ((u >> 16) & 1);   // round-to-nearest-even
    return (ushort)(u >> 16);
}

__device__ __forceinline__ float bf2f(ushort h) {
    union { unsigned u; float f; } c; c.u = (unsigned)h << 16;
    return c.f;
}

// ---------------------------------------------------------------------------
// prep: zero cursor + convert node_feats and W to bf16 (single pass)
// ---------------------------------------------------------------------------
#define NQ (N_NODES * D / 4)        // 640000 float4 quads of node_feats
#define WQ (D * 2 * D / 4)          // 32768 quads of W
__global__ __launch_bounds__(256) void prep_kernel(
    const float* __restrict__ node_feats, const float* __restrict__ W,
    ushort* __restrict__ nf_bf, ushort* __restrict__ w_bf,
    int* __restrict__ cursor) {
    const int i = blockIdx.x * blockDim.x + threadIdx.x;
    if (i < N_NODES) cursor[i] = 0;
    if (i < NQ) {
        const f32x4 v = *reinterpret_cast<const f32x4*>(node_feats + (size_t)i * 4);
        ushort4 o; o.x = f2bf(v.x); o.y = f2bf(v.y); o.z = f2bf(v.z); o.w = f2bf(v.w);
        *reinterpret_cast<ushort4*>(nf_bf + (size_t)i * 4) = o;
    } else if (i < NQ + WQ) {
        const int j = i - NQ;
        const f32x4 v = *reinterpret_cast<const f32x4*>(W + (size_t)j * 4);
        ushort4 o; o.x = f2bf(v.x); o.y = f2bf(v.y); o.z = f2bf(v.z); o.w = f2bf(v.w);
        *reinterpret_cast<ushort4*>(w_bf + (size_t)j * 4) = o;
    }
}

// ---------------------------------------------------------------------------
// direct bucket scatter: buckets[dst*BUCKET + pos] = {eid, src[eid]}
// 4 edges/thread with vectorized index reads.
// ---------------------------------------------------------------------------
__global__ __launch_bounds__(256) void scatter_direct(
    const int* __restrict__ dst, const int* __restrict__ src,
    int* __restrict__ cursor, int2* __restrict__ buckets) {
    const int q = blockIdx.x * blockDim.x + threadIdx.x;   // quad index
    const int e0 = q * 4;
    if (e0 + 3 < N_EDGES) {
        const int4 d4 = *reinterpret_cast<const int4*>(dst + e0);
        const int4 s4 = *reinterpret_cast<const int4*>(src + e0);
        int p;
        p = atomicAdd(&cursor[d4.x], 1); if (p < BUCKET) buckets[(size_t)d4.x * BUCKET + p] = make_int2(e0 + 0, s4.x);
        p = atomicAdd(&cursor[d4.y], 1); if (p < BUCKET) buckets[(size_t)d4.y * BUCKET + p] = make_int2(e0 + 1, s4.y);
        p = atomicAdd(&cursor[d4.z], 1); if (p < BUCKET) buckets[(size_t)d4.z * BUCKET + p] = make_int2(e0 + 2, s4.z);
        p = atomicAdd(&cursor[d4.w], 1); if (p < BUCKET) buckets[(size_t)d4.w * BUCKET + p] = make_int2(e0 + 3, s4.w);
    } else {
        for (int e = e0; e < N_EDGES; ++e) {
            const int d = dst[e];
            const int p = atomicAdd(&cursor[d], 1);
            if (p < BUCKET) buckets[(size_t)d * BUCKET + p] = make_int2(e, src[e]);
        }
    }
}

// ---------------------------------------------------------------------------
// One wave per node: walk the node's bucket, accumulate msg in registers.
// 8-edge unroll: 8 index loads issued together, then 16 independent row
// loads (~16KB in flight/wave), 4 accumulator chains.
// ---------------------------------------------------------------------------
__global__ __launch_bounds__(256) void gather_reduce(
    const ushort* __restrict__ nf_bf,
    const float* __restrict__ edge_feats,
    const int2* __restrict__ buckets,
    const int* __restrict__ cursor,
    ushort* __restrict__ red_bf) {
    const int node = blockIdx.x * 4 + (threadIdx.x >> 6);
    const int lane = threadIdx.x & 63;
    if (node >= N_NODES) return;
    int cnt = cursor[node];
    if (cnt > BUCKET) cnt = BUCKET;
    const int2* seg = buckets + (size_t)node * BUCKET;
    const size_t loff = (size_t)lane * 4;

    f32x4 acc0 = {0.f, 0.f, 0.f, 0.f};
    f32x4 acc1 = {0.f, 0.f, 0.f, 0.f};
    f32x4 acc2 = {0.f, 0.f, 0.f, 0.f};
    f32x4 acc3 = {0.f, 0.f, 0.f, 0.f};

    int i = 0;
    for (; i + 7 < cnt; i += 8) {
        int2 p[8];
        #pragma unroll
        for (int j = 0; j < 8; ++j) p[j] = seg[i + j];
        ushort4 h[8];
        f32x4 ef[8];
        #pragma unroll
        for (int j = 0; j < 8; ++j)
            h[j] = *reinterpret_cast<const ushort4*>(nf_bf + (size_t)p[j].y * D + loff);
        #pragma unroll
        for (int j = 0; j < 8; ++j)
            ef[j] = __builtin_nontemporal_load(
                reinterpret_cast<const f32x4*>(edge_feats + (size_t)p[j].x * D + loff));
        #pragma unroll
        for (int j = 0; j < 8; ++j) {
            const f32x4 nf = {bf2f(h[j].x), bf2f(h[j].y), bf2f(h[j].z), bf2f(h[j].w)};
            const f32x4 m = nf * ef[j];
            if ((j & 3) == 0) acc0 += m;
            else if ((j & 3) == 1) acc1 += m;
            else if ((j & 3) == 2) acc2 += m;
            else acc3 += m;
        }
    }
    for (; i + 3 < cnt; i += 4) {
        int2 p[4];
        #pragma unroll
        for (int j = 0; j < 4; ++j) p[j] = seg[i + j];
        #pragma unroll
        for (int j = 0; j < 4; ++j) {
            const ushort4 h = *reinterpret_cast<const ushort4*>(nf_bf + (size_t)p[j].y * D + loff);
            const f32x4 ef = __builtin_nontemporal_load(
                reinterpret_cast<const f32x4*>(edge_feats + (size_t)p[j].x * D + loff));
            const f32x4 nf = {bf2f(h.x), bf2f(h.y), bf2f(h.z), bf2f(h.w)};
            if (j == 0) acc0 += nf * ef;
            else if (j == 1) acc1 += nf * ef;
            else if (j == 2) acc2 += nf * ef;
            else acc3 += nf * ef;
        }
    }
    for (; i < cnt; ++i) {
        const int2 p0 = seg[i];
        const ushort4 h0 = *reinterpret_cast<const ushort4*>(nf_bf + (size_t)p0.y * D + loff);
        const f32x4 ef0 = __builtin_nontemporal_load(
            reinterpret_cast<const f32x4*>(edge_feats + (size_t)p0.x * D + loff));
        const f32x4 nf0 = {bf2f(h0.x), bf2f(h0.y), bf2f(h0.z), bf2f(h0.w)};
        acc0 += nf0 * ef0;
    }
    const f32x4 acc = (acc0 + acc1) + (acc2 + acc3);
    ushort4 o;
    o.x = f2bf(acc.x); o.y = f2bf(acc.y); o.z = f2bf(acc.z); o.w = f2bf(acc.w);
    *reinterpret_cast<ushort4*>(red_bf + (size_t)node * D + loff) = o;
}

// ---------------------------------------------------------------------------
// MFMA GEMM: out = relu(concat(nf_bf, red_bf) @ W_bf.T + b), fp32 accum.
// Register-only; 64x64 block tile, 4 waves x (32x32), mfma_f32_16x16x32_bf16.
// Nontemporal out stores (out is never re-read; keep A/W hot in L2).
// ---------------------------------------------------------------------------
__global__ __launch_bounds__(256) void mfma_gemm(
    const ushort* __restrict__ nf_bf,   // [N][256] bf16
    const ushort* __restrict__ red_bf,  // [N][256] bf16
    const ushort* __restrict__ w_bf,    // [256][512] bf16
    const float* __restrict__ bias,
    float* __restrict__ out) {
    const int lane = threadIdx.x & 63;
    const int wid  = threadIdx.x >> 6;
    const int rowBase = blockIdx.x * 64 + (wid & 1) * 32;
    const int colBase = blockIdx.y * 64 + (wid >> 1) * 32;

    const int lr = lane & 15;
    const int kh = (lane >> 4) * 8;

    int r0 = rowBase + lr;      if (r0 >= N_NODES) r0 = N_NODES - 1;
    int r1 = rowBase + 16 + lr; if (r1 >= N_NODES) r1 = N_NODES - 1;
    const int c0 = colBase + lr;
    const int c1 = c0 + 16;

    f32x4 acc00 = {0.f,0.f,0.f,0.f}, acc01 = {0.f,0.f,0.f,0.f};
    f32x4 acc10 = {0.f,0.f,0.f,0.f}, acc11 = {0.f,0.f,0.f,0.f};

    const ushort* w0 = w_bf + (size_t)c0 * 512 + kh;
    const ushort* w1 = w_bf + (size_t)c1 * 512 + kh;

    {
        const ushort* a0p = nf_bf + (size_t)r0 * 256 + kh;
        const ushort* a1p = nf_bf + (size_t)r1 * 256 + kh;
        #pragma unroll
        for (int kk = 0; kk < 8; ++kk) {
            const bf16x8 a0 = *reinterpret_cast<const bf16x8*>(a0p + kk * 32);
            const bf16x8 a1 = *reinterpret_cast<const bf16x8*>(a1p + kk * 32);
            const bf16x8 b0 = *reinterpret_cast<const bf16x8*>(w0 + kk * 32);
            const bf16x8 b1 = *reinterpret_cast<const bf16x8*>(w1 + kk * 32);
            acc00 = __builtin_amdgcn_mfma_f32_16x16x32_bf16(a0, b0, acc00, 0, 0, 0);
            acc01 = __builtin_amdgcn_mfma_f32_16x16x32_bf16(a0, b1, acc01, 0, 0, 0);
            acc10 = __builtin_amdgcn_mfma_f32_16x16x32_bf16(a1, b0, acc10, 0, 0, 0);
            acc11 = __builtin_amdgcn_mfma_f32_16x16x32_bf16(a1, b1, acc11, 0, 0, 0);
        }
    }
    {
        const ushort* a0p = red_bf + (size_t)r0 * 256 + kh;
        const ushort* a1p = red_bf + (size_t)r1 * 256 + kh;
        #pragma unroll
        for (int kk = 0; kk < 8; ++kk) {
            const bf16x8 a0 = *reinterpret_cast<const bf16x8*>(a0p + kk * 32);
            const bf16x8 a1 = *reinterpret_cast<const bf16x8*>(a1p + kk * 32);
            const bf16x8 b0 = *reinterpret_cast<const bf16x8*>(w0 + 256 + kk * 32);
            const bf16x8 b1 = *reinterpret_cast<const bf16x8*>(w1 + 256 + kk * 32);
            acc00 = __builtin_amdgcn_mfma_f32_16x16x32_bf16(a0, b0, acc00, 0, 0, 0);
            acc01 = __builtin_amdgcn_mfma_f32_16x16x32_bf16(a0, b1, acc01, 0, 0, 0);
            acc10 = __builtin_amdgcn_mfma_f32_16x16x32_bf16(a1, b0, acc10, 0, 0, 0);
            acc11 = __builtin_amdgcn_mfma_f32_16x16x32_bf16(a1, b1, acc11, 0, 0, 0);
        }
    }

    const float bc0 = bias[c0];
    const float bc1 = bias[c1];
    const int orow = (lane >> 4) * 4;
    #pragma unroll
    for (int i = 0; i < 4; ++i) {
        const int row0 = rowBase + orow + i;
        if (row0 < N_NODES) {
            __builtin_nontemporal_store(relu(acc00[i] + bc0), out + (size_t)row0 * 256 + c0);
            __builtin_nontemporal_store(relu(acc01[i] + bc1), out + (size_t)row0 * 256 + c1);
        }
        const int row1 = rowBase + 16 + orow + i;
        if (row1 < N_NODES) {
            __builtin_nontemporal_store(relu(acc10[i] + bc0), out + (size_t)row1 * 256 + c0);
            __builtin_nontemporal_store(relu(acc11[i] + bc1), out + (size_t)row1 * 256 + c1);
        }
    }
}

extern "C" void kernel_launch(void* const* d_in, const int* in_sizes, int n_in,
                              void* d_out, int out_size, void* d_ws, size_t ws_size,
                              hipStream_t stream) {
    const float* node_feats = (const float*)d_in[0];
    const float* edge_feats = (const float*)d_in[1];
    const int*   src        = (const int*)d_in[2];
    const int*   dst        = (const int*)d_in[3];
    const float* W          = (const float*)d_in[4];
    const float* bias       = (const float*)d_in[5];
    float* out = (float*)d_out;

    // workspace layout (256B-aligned slices)
    char* ws = (char*)d_ws;
    ushort* red_bf = (ushort*)ws;  ws += ((size_t)N_NODES * D * 2 + 255) & ~255ull;   // 5.12 MB
    ushort* nf_bf  = (ushort*)ws;  ws += ((size_t)N_NODES * D * 2 + 255) & ~255ull;   // 5.12 MB
    ushort* w_bf   = (ushort*)ws;  ws += ((size_t)D * 2 * D * 2 + 255) & ~255ull;     // 256 KB
    int* cursor    = (int*)ws;     ws += ((size_t)N_NODES * 4 + 255) & ~255ull;       // 40 KB
    int2* buckets  = (int2*)ws;                                                       // 10.24 MB

    prep_kernel<<<(NQ + WQ + 255) / 256, 256, 0, stream>>>(node_feats, W, nf_bf, w_bf, cursor);
    scatter_direct<<<(N_EDGES / 4 + 255) / 256, 256, 0, stream>>>(dst, src, cursor, buckets);
    gather_reduce<<<(N_NODES + 3) / 4, 256, 0, stream>>>(
        nf_bf, edge_feats, buckets, cursor, red_bf);
    dim3 grid((N_NODES + 63) / 64, 256 / 64);
    mfma_gemm<<<grid, 256, 0, stream>>>(nf_bf, red_bf, w_bf, bias, out);
}

// Round 9
// 132.332 us; speedup vs baseline: 1.0064x; 1.0064x over previous
//
#include <hip/hip_runtime.h>

#define N_NODES 10000
#define N_EDGES 320000
#define D 256
#define BUCKET 128   // int2 slots per node; degree ~ Binom(320K,1e-4), mean 32, sigma 5.7

typedef __attribute__((ext_vector_type(8))) short bf16x8;
typedef __attribute__((ext_vector_type(4))) float f32x4;

__device__ __forceinline__ float relu(float x) { return x > 0.0f ? x : 0.0f; }

__device__ __forceinline__ ushort f2bf(float f) {
    union { float f; unsigned u; } c; c.f = f;
    unsigned u = c.u;
    u += 0x7FFF + ((u >> 16) & 1);   // round-to-nearest-even
    return (ushort)(u >> 16);
}

__device__ __forceinline__ float bf2f(ushort h) {
    union { unsigned u; float f; } c; c.u = (unsigned)h << 16;
    return c.f;
}

// ---------------------------------------------------------------------------
// prep: zero cursor + convert node_feats and W to bf16 (single pass)
// ---------------------------------------------------------------------------
#define NQ (N_NODES * D / 4)        // 640000 float4 quads of node_feats
#define WQ (D * 2 * D / 4)          // 32768 quads of W
__global__ __launch_bounds__(256) void prep_kernel(
    const float* __restrict__ node_feats, const float* __restrict__ W,
    ushort* __restrict__ nf_bf, ushort* __restrict__ w_bf,
    int* __restrict__ cursor) {
    const int i = blockIdx.x * blockDim.x + threadIdx.x;
    if (i < N_NODES) cursor[i] = 0;
    if (i < NQ) {
        const f32x4 v = *reinterpret_cast<const f32x4*>(node_feats + (size_t)i * 4);
        ushort4 o; o.x = f2bf(v.x); o.y = f2bf(v.y); o.z = f2bf(v.z); o.w = f2bf(v.w);
        *reinterpret_cast<ushort4*>(nf_bf + (size_t)i * 4) = o;
    } else if (i < NQ + WQ) {
        const int j = i - NQ;
        const f32x4 v = *reinterpret_cast<const f32x4*>(W + (size_t)j * 4);
        ushort4 o; o.x = f2bf(v.x); o.y = f2bf(v.y); o.z = f2bf(v.z); o.w = f2bf(v.w);
        *reinterpret_cast<ushort4*>(w_bf + (size_t)j * 4) = o;
    }
}

// ---------------------------------------------------------------------------
// direct bucket scatter: buckets[dst*BUCKET + pos] = {eid, src[eid]}
// 4 edges/thread with vectorized index reads.
// ---------------------------------------------------------------------------
__global__ __launch_bounds__(256) void scatter_direct(
    const int* __restrict__ dst, const int* __restrict__ src,
    int* __restrict__ cursor, int2* __restrict__ buckets) {
    const int q = blockIdx.x * blockDim.x + threadIdx.x;   // quad index
    const int e0 = q * 4;
    if (e0 + 3 < N_EDGES) {
        const int4 d4 = *reinterpret_cast<const int4*>(dst + e0);
        const int4 s4 = *reinterpret_cast<const int4*>(src + e0);
        int p;
        p = atomicAdd(&cursor[d4.x], 1); if (p < BUCKET) buckets[(size_t)d4.x * BUCKET + p] = make_int2(e0 + 0, s4.x);
        p = atomicAdd(&cursor[d4.y], 1); if (p < BUCKET) buckets[(size_t)d4.y * BUCKET + p] = make_int2(e0 + 1, s4.y);
        p = atomicAdd(&cursor[d4.z], 1); if (p < BUCKET) buckets[(size_t)d4.z * BUCKET + p] = make_int2(e0 + 2, s4.z);
        p = atomicAdd(&cursor[d4.w], 1); if (p < BUCKET) buckets[(size_t)d4.w * BUCKET + p] = make_int2(e0 + 3, s4.w);
    } else {
        for (int e = e0; e < N_EDGES; ++e) {
            const int d = dst[e];
            const int p = atomicAdd(&cursor[d], 1);
            if (p < BUCKET) buckets[(size_t)d * BUCKET + p] = make_int2(e, src[e]);
        }
    }
}

// ---------------------------------------------------------------------------
// One wave per node: walk the node's bucket, accumulate msg in registers.
// 4-edge unroll (measured best R7); HBM-bound ef loads issued before the
// L2/L3-resident nf loads so the long-latency stream is in flight first.
// ---------------------------------------------------------------------------
__global__ __launch_bounds__(256) void gather_reduce(
    const ushort* __restrict__ nf_bf,
    const float* __restrict__ edge_feats,
    const int2* __restrict__ buckets,
    const int* __restrict__ cursor,
    ushort* __restrict__ red_bf) {
    const int node = blockIdx.x * 4 + (threadIdx.x >> 6);
    const int lane = threadIdx.x & 63;
    if (node >= N_NODES) return;
    int cnt = cursor[node];
    if (cnt > BUCKET) cnt = BUCKET;
    const int2* seg = buckets + (size_t)node * BUCKET;
    const size_t loff = (size_t)lane * 4;

    f32x4 acc0 = {0.f, 0.f, 0.f, 0.f};
    f32x4 acc1 = {0.f, 0.f, 0.f, 0.f};
    f32x4 acc2 = {0.f, 0.f, 0.f, 0.f};
    f32x4 acc3 = {0.f, 0.f, 0.f, 0.f};

    int i = 0;
    for (; i + 3 < cnt; i += 4) {
        const int2 p0 = seg[i];
        const int2 p1 = seg[i + 1];
        const int2 p2 = seg[i + 2];
        const int2 p3 = seg[i + 3];
        // HBM loads first
        const f32x4 ef0 = __builtin_nontemporal_load(
            reinterpret_cast<const f32x4*>(edge_feats + (size_t)p0.x * D + loff));
        const f32x4 ef1 = __builtin_nontemporal_load(
            reinterpret_cast<const f32x4*>(edge_feats + (size_t)p1.x * D + loff));
        const f32x4 ef2 = __builtin_nontemporal_load(
            reinterpret_cast<const f32x4*>(edge_feats + (size_t)p2.x * D + loff));
        const f32x4 ef3 = __builtin_nontemporal_load(
            reinterpret_cast<const f32x4*>(edge_feats + (size_t)p3.x * D + loff));
        // cache-resident loads second
        const ushort4 h0 = *reinterpret_cast<const ushort4*>(nf_bf + (size_t)p0.y * D + loff);
        const ushort4 h1 = *reinterpret_cast<const ushort4*>(nf_bf + (size_t)p1.y * D + loff);
        const ushort4 h2 = *reinterpret_cast<const ushort4*>(nf_bf + (size_t)p2.y * D + loff);
        const ushort4 h3 = *reinterpret_cast<const ushort4*>(nf_bf + (size_t)p3.y * D + loff);
        const f32x4 nf0 = {bf2f(h0.x), bf2f(h0.y), bf2f(h0.z), bf2f(h0.w)};
        const f32x4 nf1 = {bf2f(h1.x), bf2f(h1.y), bf2f(h1.z), bf2f(h1.w)};
        const f32x4 nf2 = {bf2f(h2.x), bf2f(h2.y), bf2f(h2.z), bf2f(h2.w)};
        const f32x4 nf3 = {bf2f(h3.x), bf2f(h3.y), bf2f(h3.z), bf2f(h3.w)};
        acc0 += nf0 * ef0;
        acc1 += nf1 * ef1;
        acc2 += nf2 * ef2;
        acc3 += nf3 * ef3;
    }
    for (; i < cnt; ++i) {
        const int2 p0 = seg[i];
        const f32x4 ef0 = __builtin_nontemporal_load(
            reinterpret_cast<const f32x4*>(edge_feats + (size_t)p0.x * D + loff));
        const ushort4 h0 = *reinterpret_cast<const ushort4*>(nf_bf + (size_t)p0.y * D + loff);
        const f32x4 nf0 = {bf2f(h0.x), bf2f(h0.y), bf2f(h0.z), bf2f(h0.w)};
        acc0 += nf0 * ef0;
    }
    const f32x4 acc = (acc0 + acc1) + (acc2 + acc3);
    ushort4 o;
    o.x = f2bf(acc.x); o.y = f2bf(acc.y); o.z = f2bf(acc.z); o.w = f2bf(acc.w);
    *reinterpret_cast<ushort4*>(red_bf + (size_t)node * D + loff) = o;
}

// ---------------------------------------------------------------------------
// MFMA GEMM: out = relu(concat(nf_bf, red_bf) @ W_bf.T + b), fp32 accum.
// Register-only; 64x64 block tile, 4 waves x (32x32), mfma_f32_16x16x32_bf16.
// Nontemporal out stores (out is never re-read; keep A/W hot in L2).
// ---------------------------------------------------------------------------
__global__ __launch_bounds__(256) void mfma_gemm(
    const ushort* __restrict__ nf_bf,   // [N][256] bf16
    const ushort* __restrict__ red_bf,  // [N][256] bf16
    const ushort* __restrict__ w_bf,    // [256][512] bf16
    const float* __restrict__ bias,
    float* __restrict__ out) {
    const int lane = threadIdx.x & 63;
    const int wid  = threadIdx.x >> 6;
    const int rowBase = blockIdx.x * 64 + (wid & 1) * 32;
    const int colBase = blockIdx.y * 64 + (wid >> 1) * 32;

    const int lr = lane & 15;
    const int kh = (lane >> 4) * 8;

    int r0 = rowBase + lr;      if (r0 >= N_NODES) r0 = N_NODES - 1;
    int r1 = rowBase + 16 + lr; if (r1 >= N_NODES) r1 = N_NODES - 1;
    const int c0 = colBase + lr;
    const int c1 = c0 + 16;

    f32x4 acc00 = {0.f,0.f,0.f,0.f}, acc01 = {0.f,0.f,0.f,0.f};
    f32x4 acc10 = {0.f,0.f,0.f,0.f}, acc11 = {0.f,0.f,0.f,0.f};

    const ushort* w0 = w_bf + (size_t)c0 * 512 + kh;
    const ushort* w1 = w_bf + (size_t)c1 * 512 + kh;

    {
        const ushort* a0p = nf_bf + (size_t)r0 * 256 + kh;
        const ushort* a1p = nf_bf + (size_t)r1 * 256 + kh;
        #pragma unroll
        for (int kk = 0; kk < 8; ++kk) {
            const bf16x8 a0 = *reinterpret_cast<const bf16x8*>(a0p + kk * 32);
            const bf16x8 a1 = *reinterpret_cast<const bf16x8*>(a1p + kk * 32);
            const bf16x8 b0 = *reinterpret_cast<const bf16x8*>(w0 + kk * 32);
            const bf16x8 b1 = *reinterpret_cast<const bf16x8*>(w1 + kk * 32);
            acc00 = __builtin_amdgcn_mfma_f32_16x16x32_bf16(a0, b0, acc00, 0, 0, 0);
            acc01 = __builtin_amdgcn_mfma_f32_16x16x32_bf16(a0, b1, acc01, 0, 0, 0);
            acc10 = __builtin_amdgcn_mfma_f32_16x16x32_bf16(a1, b0, acc10, 0, 0, 0);
            acc11 = __builtin_amdgcn_mfma_f32_16x16x32_bf16(a1, b1, acc11, 0, 0, 0);
        }
    }
    {
        const ushort* a0p = red_bf + (size_t)r0 * 256 + kh;
        const ushort* a1p = red_bf + (size_t)r1 * 256 + kh;
        #pragma unroll
        for (int kk = 0; kk < 8; ++kk) {
            const bf16x8 a0 = *reinterpret_cast<const bf16x8*>(a0p + kk * 32);
            const bf16x8 a1 = *reinterpret_cast<const bf16x8*>(a1p + kk * 32);
            const bf16x8 b0 = *reinterpret_cast<const bf16x8*>(w0 + 256 + kk * 32);
            const bf16x8 b1 = *reinterpret_cast<const bf16x8*>(w1 + 256 + kk * 32);
            acc00 = __builtin_amdgcn_mfma_f32_16x16x32_bf16(a0, b0, acc00, 0, 0, 0);
            acc01 = __builtin_amdgcn_mfma_f32_16x16x32_bf16(a0, b1, acc01, 0, 0, 0);
            acc10 = __builtin_amdgcn_mfma_f32_16x16x32_bf16(a1, b0, acc10, 0, 0, 0);
            acc11 = __builtin_amdgcn_mfma_f32_16x16x32_bf16(a1, b1, acc11, 0, 0, 0);
        }
    }

    const float bc0 = bias[c0];
    const float bc1 = bias[c1];
    const int orow = (lane >> 4) * 4;
    #pragma unroll
    for (int i = 0; i < 4; ++i) {
        const int row0 = rowBase + orow + i;
        if (row0 < N_NODES) {
            __builtin_nontemporal_store(relu(acc00[i] + bc0), out + (size_t)row0 * 256 + c0);
            __builtin_nontemporal_store(relu(acc01[i] + bc1), out + (size_t)row0 * 256 + c1);
        }
        const int row1 = rowBase + 16 + orow + i;
        if (row1 < N_NODES) {
            __builtin_nontemporal_store(relu(acc10[i] + bc0), out + (size_t)row1 * 256 + c0);
            __builtin_nontemporal_store(relu(acc11[i] + bc1), out + (size_t)row1 * 256 + c1);
        }
    }
}

extern "C" void kernel_launch(void* const* d_in, const int* in_sizes, int n_in,
                              void* d_out, int out_size, void* d_ws, size_t ws_size,
                              hipStream_t stream) {
    const float* node_feats = (const float*)d_in[0];
    const float* edge_feats = (const float*)d_in[1];
    const int*   src        = (const int*)d_in[2];
    const int*   dst        = (const int*)d_in[3];
    const float* W          = (const float*)d_in[4];
    const float* bias       = (const float*)d_in[5];
    float* out = (float*)d_out;

    // workspace layout (256B-aligned slices)
    char* ws = (char*)d_ws;
    ushort* red_bf = (ushort*)ws;  ws += ((size_t)N_NODES * D * 2 + 255) & ~255ull;   // 5.12 MB
    ushort* nf_bf  = (ushort*)ws;  ws += ((size_t)N_NODES * D * 2 + 255) & ~255ull;   // 5.12 MB
    ushort* w_bf   = (ushort*)ws;  ws += ((size_t)D * 2 * D * 2 + 255) & ~255ull;     // 256 KB
    int* cursor    = (int*)ws;     ws += ((size_t)N_NODES * 4 + 255) & ~255ull;       // 40 KB
    int2* buckets  = (int2*)ws;                                                       // 10.24 MB

    prep_kernel<<<(NQ + WQ + 255) / 256, 256, 0, stream>>>(node_feats, W, nf_bf, w_bf, cursor);
    scatter_direct<<<(N_EDGES / 4 + 255) / 256, 256, 0, stream>>>(dst, src, cursor, buckets);
    gather_reduce<<<(N_NODES + 3) / 4, 256, 0, stream>>>(
        nf_bf, edge_feats, buckets, cursor, red_bf);
    dim3 grid((N_NODES + 63) / 64, 256 / 64);
    mfma_gemm<<<grid, 256, 0, stream>>>(nf_bf, red_bf, w_bf, bias, out);
}